// Round 4
// baseline (490.635 us; speedup 1.0000x reference)
//
#include <hip/hip_runtime.h>

#define N_NODES 50000
#define N_EDGES 800000
#define IN_DIM 128
#define OUT_DIM 64

#define GROUP_SHIFT 6                 // 64 rows per group
#define GROUP_ROWS 64
#define N_GROUPS 782                  // ceil(50000/64)
#define CHUNK 8192                    // edges per hist/fill block
#define FILL_BLOCKS 98                // 98*8192 = 802816 >= 800000

// bf16 helpers (support stored bf16; accumulation fp32)
static __device__ __forceinline__ unsigned short f2bf(float f) {
    unsigned u = __float_as_uint(f);
    unsigned r = u + 0x7fff + ((u >> 16) & 1);
    return (unsigned short)(r >> 16);
}
static __device__ __forceinline__ float bf2f(unsigned short b) {
    return __uint_as_float((unsigned)b << 16);
}

// ---------------------------------------------------------------------------
// Phase 1: support = x @ weight  (fp32 VALU GEMM, bf16 store)  [unchanged]
// ---------------------------------------------------------------------------
__global__ __launch_bounds__(256) void gemm_kernel(const float* __restrict__ x,
                                                   const float* __restrict__ w,
                                                   unsigned short* __restrict__ support) {
    __shared__ float w_lds[IN_DIM * OUT_DIM];
    __shared__ float x_lds[16 * (IN_DIM + 1)];

    for (int i = threadIdx.x; i < IN_DIM * OUT_DIM; i += 256)
        w_lds[i] = w[i];

    const int lane  = threadIdx.x & 15;
    const int local = threadIdx.x >> 4;

    for (int node_base = blockIdx.x * 16; node_base < N_NODES;
         node_base += gridDim.x * 16) {
        __syncthreads();
        for (int i = threadIdx.x; i < 16 * IN_DIM; i += 256) {
            int node = node_base + (i >> 7);
            int k    = i & 127;
            x_lds[(i >> 7) * (IN_DIM + 1) + k] =
                (node < N_NODES) ? x[(size_t)node * IN_DIM + k] : 0.0f;
        }
        __syncthreads();

        int node = node_base + local;
        if (node < N_NODES) {
            float acc0 = 0.f, acc1 = 0.f, acc2 = 0.f, acc3 = 0.f;
            const float* xr = &x_lds[local * (IN_DIM + 1)];
            #pragma unroll 8
            for (int k = 0; k < IN_DIM; ++k) {
                float  xv = xr[k];
                float4 wv = *(const float4*)&w_lds[k * OUT_DIM + lane * 4];
                acc0 += xv * wv.x;
                acc1 += xv * wv.y;
                acc2 += xv * wv.z;
                acc3 += xv * wv.w;
            }
            ushort4 o;
            o.x = f2bf(acc0); o.y = f2bf(acc1); o.z = f2bf(acc2); o.w = f2bf(acc3);
            *(ushort4*)&support[(size_t)node * OUT_DIM + lane * 4] = o;
        }
    }
}

// ---------------------------------------------------------------------------
// Phase 2a: coarse histogram (LDS-staged; ~77K global atomics total)
// ---------------------------------------------------------------------------
__global__ __launch_bounds__(256) void hist2_kernel(const int* __restrict__ erow,
                                                    int* __restrict__ ghist) {
    __shared__ int lcnt[N_GROUPS];
    for (int i = threadIdx.x; i < N_GROUPS; i += 256) lcnt[i] = 0;
    __syncthreads();
    const int base = blockIdx.x * CHUNK;
    #pragma unroll 4
    for (int i = 0; i < CHUNK / 256; ++i) {
        int e = base + threadIdx.x + i * 256;
        if (e < N_EDGES) atomicAdd(&lcnt[erow[e] >> GROUP_SHIFT], 1);
    }
    __syncthreads();
    for (int i = threadIdx.x; i < N_GROUPS; i += 256) {
        int c = lcnt[i];
        if (c) atomicAdd(&ghist[i], c);
    }
}

// ---------------------------------------------------------------------------
// Phase 2b: exclusive scan of 782 group counts (single block, 16 waves)
// ---------------------------------------------------------------------------
__global__ __launch_bounds__(1024) void scan2_kernel(const int* __restrict__ ghist,
                                                     int* __restrict__ goffs,
                                                     int* __restrict__ gcursor) {
    __shared__ int wsum[16];
    const int tid  = threadIdx.x;
    const int lane = tid & 63;
    const int wid  = tid >> 6;
    int v = (tid < N_GROUPS) ? ghist[tid] : 0;
    int s = v;
    #pragma unroll
    for (int off = 1; off < 64; off <<= 1) {
        int t = __shfl_up(s, off, 64);
        if (lane >= off) s += t;
    }
    if (lane == 63) wsum[wid] = s;
    __syncthreads();
    if (wid == 0 && lane < 16) {
        int wv = wsum[lane];
        #pragma unroll
        for (int off = 1; off < 16; off <<= 1) {
            int t = __shfl_up(wv, off, 64);
            if (lane >= off) wv += t;
        }
        wsum[lane] = wv;
    }
    __syncthreads();
    int excl = s - v + ((wid > 0) ? wsum[wid - 1] : 0);
    if (tid < N_GROUPS) { goffs[tid] = excl; gcursor[tid] = excl; }
}

// ---------------------------------------------------------------------------
// Phase 2c: coarse-grouped fill.  Per block: LDS count -> one global
// reservation per touched bin -> write entries at gbase[g]+p (runs of ~10
// contiguous 8B entries per bin per block -> ~14 B/edge HBM writes).
// Entry: x = (row&63)<<16 | col   (col < 65536), y = val bits.
// ---------------------------------------------------------------------------
__global__ __launch_bounds__(256) void fill2_kernel(const int* __restrict__ erow,
                                                    const int* __restrict__ ecol,
                                                    const float* __restrict__ eval,
                                                    int* __restrict__ gcursor,
                                                    int2* __restrict__ bucket) {
    __shared__ int lcnt[N_GROUPS];
    __shared__ int lbase[N_GROUPS];
    for (int i = threadIdx.x; i < N_GROUPS; i += 256) lcnt[i] = 0;
    __syncthreads();
    const int base = blockIdx.x * CHUNK;
    // pass A: local count
    #pragma unroll 4
    for (int i = 0; i < CHUNK / 256; ++i) {
        int e = base + threadIdx.x + i * 256;
        if (e < N_EDGES) atomicAdd(&lcnt[erow[e] >> GROUP_SHIFT], 1);
    }
    __syncthreads();
    // pass B: reserve a contiguous run per touched bin; reset local cursors
    for (int i = threadIdx.x; i < N_GROUPS; i += 256) {
        int c = lcnt[i];
        lbase[i] = c ? atomicAdd(&gcursor[i], c) : 0;
        lcnt[i]  = 0;
    }
    __syncthreads();
    // pass C: re-read edges (L1/L2 hot) and place them
    #pragma unroll 4
    for (int i = 0; i < CHUNK / 256; ++i) {
        int e = base + threadIdx.x + i * 256;
        if (e < N_EDGES) {
            int r = erow[e];
            int g = r >> GROUP_SHIFT;
            int p = atomicAdd(&lcnt[g], 1);
            bucket[lbase[g] + p] =
                make_int2(((r & (GROUP_ROWS - 1)) << 16) | ecol[e],
                          __float_as_int(eval[e]));
        }
    }
}

// ---------------------------------------------------------------------------
// Phase 3: per-group reduce.  One block per 64-row group; fp32 accumulators
// in LDS, transposed layout acc[col][row] with stride 65 (65%32==1 spreads
// banks; plain stride-64 would be a 16-way conflict on ds_add).
// 16 lanes per edge, ushort4 support gather, fused ReLU writeout.
// ---------------------------------------------------------------------------
__global__ __launch_bounds__(512) void reduce2_kernel(const int* __restrict__ goffs,
                                                      const int2* __restrict__ bucket,
                                                      const unsigned short* __restrict__ support,
                                                      float* __restrict__ out) {
    __shared__ float acc[OUT_DIM * (GROUP_ROWS + 1)];   // 64*65 fp32 = 16.6 KB
    const int g4 = threadIdx.x & 15;    // column group: cols 4*g4 .. 4*g4+3
    const int sg = threadIdx.x >> 4;    // sub-group 0..31, one edge each

    for (int i = threadIdx.x; i < OUT_DIM * (GROUP_ROWS + 1); i += 512)
        acc[i] = 0.f;
    __syncthreads();

    const int grp   = blockIdx.x;
    const int start = goffs[grp];
    const int end   = (grp == N_GROUPS - 1) ? N_EDGES : goffs[grp + 1];

    for (int j = start + sg; j < end; j += 32) {
        int2 cv  = bucket[j];
        int  rl  = cv.x >> 16;
        int  col = cv.x & 0xFFFF;
        float v  = __int_as_float(cv.y);
        ushort4 sr = *(const ushort4*)&support[(size_t)col * OUT_DIM + g4 * 4];
        int b0 = (4 * g4 + 0) * (GROUP_ROWS + 1) + rl;
        atomicAdd(&acc[b0],                       v * bf2f(sr.x));
        atomicAdd(&acc[b0 + 1 * (GROUP_ROWS + 1)], v * bf2f(sr.y));
        atomicAdd(&acc[b0 + 2 * (GROUP_ROWS + 1)], v * bf2f(sr.z));
        atomicAdd(&acc[b0 + 3 * (GROUP_ROWS + 1)], v * bf2f(sr.w));
    }
    __syncthreads();

    // writeout: 64 rows x 64 cols, float4 per thread-item, gather from
    // transposed LDS with 4 b32 reads
    const int rbase = grp * GROUP_ROWS;
    for (int i = threadIdx.x; i < GROUP_ROWS * 16; i += 512) {
        int rl   = i >> 4;
        int cg   = i & 15;
        int row  = rbase + rl;
        if (row < N_NODES) {
            float4 a;
            a.x = acc[(4 * cg + 0) * (GROUP_ROWS + 1) + rl];
            a.y = acc[(4 * cg + 1) * (GROUP_ROWS + 1) + rl];
            a.z = acc[(4 * cg + 2) * (GROUP_ROWS + 1) + rl];
            a.w = acc[(4 * cg + 3) * (GROUP_ROWS + 1) + rl];
            a.x = fmaxf(a.x, 0.f);
            a.y = fmaxf(a.y, 0.f);
            a.z = fmaxf(a.z, 0.f);
            a.w = fmaxf(a.w, 0.f);
            *(float4*)&out[(size_t)row * OUT_DIM + cg * 4] = a;
        }
    }
}

extern "C" void kernel_launch(void* const* d_in, const int* in_sizes, int n_in,
                              void* d_out, int out_size, void* d_ws, size_t ws_size,
                              hipStream_t stream) {
    const float* x    = (const float*)d_in[0];
    const int*   erow = (const int*)  d_in[1];
    const int*   ecol = (const int*)  d_in[2];
    const float* ev   = (const float*)d_in[3];
    const float* w    = (const float*)d_in[4];
    float* out = (float*)d_out;

    // workspace layout (16B-aligned)
    char* ws = (char*)d_ws;
    unsigned short* support = (unsigned short*)ws;   // 6,400,000 B
    int*  ghist   = (int*)(ws + 6400000);            //     3,128 B
    int*  goffs   = (int*)(ws + 6403200);            //     3,128 B
    int*  gcursor = (int*)(ws + 6406400);            //     3,128 B
    int2* bucket  = (int2*)(ws + 6409600);           // 6,400,000 B  (~12.8 MB)

    hipMemsetAsync(ghist, 0, sizeof(int) * N_GROUPS, stream);

    gemm_kernel<<<(N_NODES + 15) / 16, 256, 0, stream>>>(x, w, support);

    hist2_kernel<<<FILL_BLOCKS, 256, 0, stream>>>(erow, ghist);
    scan2_kernel<<<1, 1024, 0, stream>>>(ghist, goffs, gcursor);
    fill2_kernel<<<FILL_BLOCKS, 256, 0, stream>>>(erow, ecol, ev, gcursor, bucket);
    reduce2_kernel<<<N_GROUPS, 512, 0, stream>>>(goffs, bucket, support, out);
}

// Round 5
// 191.543 us; speedup vs baseline: 2.5615x; 2.5615x over previous
//
#include <hip/hip_runtime.h>

#define N_NODES 50000
#define N_EDGES 800000
#define IN_DIM 128
#define OUT_DIM 64

#define GROUP_SHIFT 6                 // 64 rows per group
#define GROUP_ROWS 64
#define N_GROUPS 782                  // ceil(50000/64)
#define CHUNK 8192                    // edges per hist/fill block
#define FILL_BLOCKS 98                // 98*8192 >= 800000

// bf16 helpers (support stored bf16; accumulation fp32)
static __device__ __forceinline__ unsigned short f2bf(float f) {
    unsigned u = __float_as_uint(f);
    unsigned r = u + 0x7fff + ((u >> 16) & 1);
    return (unsigned short)(r >> 16);
}
static __device__ __forceinline__ float bf2f(unsigned short b) {
    return __uint_as_float((unsigned)b << 16);
}

// ---------------------------------------------------------------------------
// Phase 1: support = x @ weight  (fp32 VALU GEMM, bf16 store)
// ---------------------------------------------------------------------------
__global__ __launch_bounds__(256) void gemm_kernel(const float* __restrict__ x,
                                                   const float* __restrict__ w,
                                                   unsigned short* __restrict__ support) {
    __shared__ float w_lds[IN_DIM * OUT_DIM];
    __shared__ float x_lds[16 * (IN_DIM + 1)];

    for (int i = threadIdx.x; i < IN_DIM * OUT_DIM; i += 256)
        w_lds[i] = w[i];

    const int lane  = threadIdx.x & 15;
    const int local = threadIdx.x >> 4;

    for (int node_base = blockIdx.x * 16; node_base < N_NODES;
         node_base += gridDim.x * 16) {
        __syncthreads();
        for (int i = threadIdx.x; i < 16 * IN_DIM; i += 256) {
            int node = node_base + (i >> 7);
            int k    = i & 127;
            x_lds[(i >> 7) * (IN_DIM + 1) + k] =
                (node < N_NODES) ? x[(size_t)node * IN_DIM + k] : 0.0f;
        }
        __syncthreads();

        int node = node_base + local;
        if (node < N_NODES) {
            float acc0 = 0.f, acc1 = 0.f, acc2 = 0.f, acc3 = 0.f;
            const float* xr = &x_lds[local * (IN_DIM + 1)];
            #pragma unroll 8
            for (int k = 0; k < IN_DIM; ++k) {
                float  xv = xr[k];
                float4 wv = *(const float4*)&w_lds[k * OUT_DIM + lane * 4];
                acc0 += xv * wv.x;
                acc1 += xv * wv.y;
                acc2 += xv * wv.z;
                acc3 += xv * wv.w;
            }
            ushort4 o;
            o.x = f2bf(acc0); o.y = f2bf(acc1); o.z = f2bf(acc2); o.w = f2bf(acc3);
            *(ushort4*)&support[(size_t)node * OUT_DIM + lane * 4] = o;
        }
    }
}

// ---------------------------------------------------------------------------
// Phase 2a: coarse histogram of edge_row >> 6  (LDS-staged)
// ---------------------------------------------------------------------------
__global__ __launch_bounds__(256) void hist2_kernel(const int* __restrict__ erow,
                                                    int* __restrict__ ghist) {
    __shared__ int lcnt[N_GROUPS];
    for (int i = threadIdx.x; i < N_GROUPS; i += 256) lcnt[i] = 0;
    __syncthreads();
    const int base = blockIdx.x * CHUNK;
    #pragma unroll 4
    for (int i = 0; i < CHUNK / 256; ++i) {
        int e = base + threadIdx.x + i * 256;
        if (e < N_EDGES) atomicAdd(&lcnt[erow[e] >> GROUP_SHIFT], 1);
    }
    __syncthreads();
    for (int i = threadIdx.x; i < N_GROUPS; i += 256) {
        int c = lcnt[i];
        if (c) atomicAdd(&ghist[i], c);
    }
}

// ---------------------------------------------------------------------------
// Phase 2b: exclusive scan of 782 group counts
// ---------------------------------------------------------------------------
__global__ __launch_bounds__(1024) void scan2_kernel(const int* __restrict__ ghist,
                                                     int* __restrict__ goffs,
                                                     int* __restrict__ gcursor) {
    __shared__ int wsum[16];
    const int tid  = threadIdx.x;
    const int lane = tid & 63;
    const int wid  = tid >> 6;
    int v = (tid < N_GROUPS) ? ghist[tid] : 0;
    int s = v;
    #pragma unroll
    for (int off = 1; off < 64; off <<= 1) {
        int t = __shfl_up(s, off, 64);
        if (lane >= off) s += t;
    }
    if (lane == 63) wsum[wid] = s;
    __syncthreads();
    if (wid == 0 && lane < 16) {
        int wv = wsum[lane];
        #pragma unroll
        for (int off = 1; off < 16; off <<= 1) {
            int t = __shfl_up(wv, off, 64);
            if (lane >= off) wv += t;
        }
        wsum[lane] = wv;
    }
    __syncthreads();
    int excl = s - v + ((wid > 0) ? wsum[wid - 1] : 0);
    if (tid < N_GROUPS) { goffs[tid] = excl; gcursor[tid] = excl; }
}

// ---------------------------------------------------------------------------
// Phase 2c: coarse-grouped fill (block-level reservation, low write-amp).
// Entry: x = (row&63)<<16 | col, y = val bits.
// ---------------------------------------------------------------------------
__global__ __launch_bounds__(256) void fill2_kernel(const int* __restrict__ erow,
                                                    const int* __restrict__ ecol,
                                                    const float* __restrict__ eval,
                                                    int* __restrict__ gcursor,
                                                    int2* __restrict__ bucket) {
    __shared__ int lcnt[N_GROUPS];
    __shared__ int lbase[N_GROUPS];
    for (int i = threadIdx.x; i < N_GROUPS; i += 256) lcnt[i] = 0;
    __syncthreads();
    const int base = blockIdx.x * CHUNK;
    #pragma unroll 4
    for (int i = 0; i < CHUNK / 256; ++i) {
        int e = base + threadIdx.x + i * 256;
        if (e < N_EDGES) atomicAdd(&lcnt[erow[e] >> GROUP_SHIFT], 1);
    }
    __syncthreads();
    for (int i = threadIdx.x; i < N_GROUPS; i += 256) {
        int c = lcnt[i];
        lbase[i] = c ? atomicAdd(&gcursor[i], c) : 0;
        lcnt[i]  = 0;
    }
    __syncthreads();
    #pragma unroll 4
    for (int i = 0; i < CHUNK / 256; ++i) {
        int e = base + threadIdx.x + i * 256;
        if (e < N_EDGES) {
            int r = erow[e];
            int g = r >> GROUP_SHIFT;
            int p = atomicAdd(&lcnt[g], 1);
            bucket[lbase[g] + p] =
                make_int2(((r & (GROUP_ROWS - 1)) << 16) | ecol[e],
                          __float_as_int(eval[e]));
        }
    }
}

// ---------------------------------------------------------------------------
// Phase 2d: per-group counting sort -> exact per-row CSR (bucket2 + offs).
// One block per group (~1024 edges).  Scattered writes land in an 8 KB
// window -> L2 dirties whole lines -> ~1x HBM write amplification.
// ---------------------------------------------------------------------------
__global__ __launch_bounds__(256) void sort_kernel(const int* __restrict__ goffs,
                                                   const int2* __restrict__ bucket,
                                                   int2* __restrict__ bucket2,
                                                   int* __restrict__ offs) {
    __shared__ int rcnt[GROUP_ROWS];
    __shared__ int rbase_s[GROUP_ROWS];   // exclusive scan of rcnt
    const int grp   = blockIdx.x;
    const int start = goffs[grp];
    const int end   = (grp == N_GROUPS - 1) ? N_EDGES : goffs[grp + 1];
    const int tid   = threadIdx.x;

    if (tid < GROUP_ROWS) rcnt[tid] = 0;
    __syncthreads();
    for (int j = start + tid; j < end; j += 256)
        atomicAdd(&rcnt[(bucket[j].x >> 16)], 1);
    __syncthreads();
    // wave 0 scans the 64 row counts
    if (tid < 64) {
        int v = rcnt[tid];
        int s = v;
        #pragma unroll
        for (int off = 1; off < 64; off <<= 1) {
            int t = __shfl_up(s, off, 64);
            if (tid >= off) s += t;
        }
        int excl = s - v;
        rbase_s[tid] = excl;
        int row = grp * GROUP_ROWS + tid;
        if (row < N_NODES) offs[row] = start + excl;
        rcnt[tid] = 0;   // reuse as cursor
    }
    __syncthreads();
    for (int j = start + tid; j < end; j += 256) {
        int2 cv = bucket[j];
        int rl = cv.x >> 16;
        int p  = atomicAdd(&rcnt[rl], 1);
        bucket2[start + rbase_s[rl] + p] = cv;
    }
}

// ---------------------------------------------------------------------------
// Phase 3: per-row gather-reduce + fused ReLU (register accumulation,
// zero atomics) — the proven R3 design, reading the sorted bucket2.
// ---------------------------------------------------------------------------
__global__ __launch_bounds__(256) void reduce_kernel(const int* __restrict__ offs,
                                                     const int2* __restrict__ bucket2,
                                                     const unsigned short* __restrict__ support,
                                                     float* __restrict__ out) {
    const int g     = threadIdx.x & 15;
    const int local = threadIdx.x >> 4;
    const int row   = blockIdx.x * 16 + local;
    if (row >= N_NODES) return;
    const int start = offs[row];
    const int end   = (row == N_NODES - 1) ? N_EDGES : offs[row + 1];
    float4 acc = make_float4(0.f, 0.f, 0.f, 0.f);
    for (int j = start; j < end; ++j) {
        int2 cv = bucket2[j];
        int col = cv.x & 0xFFFF;
        float v = __int_as_float(cv.y);
        ushort4 sr = *(const ushort4*)&support[(size_t)col * OUT_DIM + g * 4];
        acc.x += v * bf2f(sr.x);
        acc.y += v * bf2f(sr.y);
        acc.z += v * bf2f(sr.z);
        acc.w += v * bf2f(sr.w);
    }
    acc.x = fmaxf(acc.x, 0.f);
    acc.y = fmaxf(acc.y, 0.f);
    acc.z = fmaxf(acc.z, 0.f);
    acc.w = fmaxf(acc.w, 0.f);
    *(float4*)&out[(size_t)row * OUT_DIM + g * 4] = acc;
}

extern "C" void kernel_launch(void* const* d_in, const int* in_sizes, int n_in,
                              void* d_out, int out_size, void* d_ws, size_t ws_size,
                              hipStream_t stream) {
    const float* x    = (const float*)d_in[0];
    const int*   erow = (const int*)  d_in[1];
    const int*   ecol = (const int*)  d_in[2];
    const float* ev   = (const float*)d_in[3];
    const float* w    = (const float*)d_in[4];
    float* out = (float*)d_out;

    // workspace layout (16B-aligned)
    char* ws = (char*)d_ws;
    unsigned short* support = (unsigned short*)ws;   //  6,400,000 B
    int*  ghist   = (int*)(ws +  6400000);           //      3,128 B
    int*  goffs   = (int*)(ws +  6403200);           //      3,128 B
    int*  gcursor = (int*)(ws +  6406400);           //      3,128 B
    int*  offs    = (int*)(ws +  6409600);           //    200,000 B
    int2* bucket  = (int2*)(ws + 6609600);           //  6,400,000 B
    int2* bucket2 = (int2*)(ws + 13009600);          //  6,400,000 B (~19.4 MB)

    hipMemsetAsync(ghist, 0, sizeof(int) * N_GROUPS, stream);

    gemm_kernel<<<(N_NODES + 15) / 16, 256, 0, stream>>>(x, w, support);

    hist2_kernel<<<FILL_BLOCKS, 256, 0, stream>>>(erow, ghist);
    scan2_kernel<<<1, 1024, 0, stream>>>(ghist, goffs, gcursor);
    fill2_kernel<<<FILL_BLOCKS, 256, 0, stream>>>(erow, ecol, ev, gcursor, bucket);
    sort_kernel<<<N_GROUPS, 256, 0, stream>>>(goffs, bucket, bucket2, offs);
    reduce_kernel<<<(N_NODES + 15) / 16, 256, 0, stream>>>(offs, bucket2, support, out);
}

// Round 6
// 150.333 us; speedup vs baseline: 3.2637x; 1.2741x over previous
//
#include <hip/hip_runtime.h>

#define N_NODES 50000
#define N_EDGES 800000
#define IN_DIM 128
#define OUT_DIM 64

#define GROUP_SHIFT 6                 // 64 rows per group
#define GROUP_ROWS 64
#define N_GROUPS 782                  // ceil(50000/64)
#define SLAB 1216                     // slab capacity per group (mean 1024, +6 sigma)
#define CHUNK2 2048                   // edges per fill block
#define FILL3_BLOCKS 391              // 391*2048 >= 800000

typedef _Float16 h4 __attribute__((ext_vector_type(4)));
typedef _Float16 h8 __attribute__((ext_vector_type(8)));
typedef float    f4 __attribute__((ext_vector_type(4)));

#define LDK 136    // padded fp16 K-stride: 272 B row pitch -> 2-way bank alias (free)

// ---------------------------------------------------------------------------
// Phase 1: support = x @ weight via MFMA fp16 (fp32 accumulate, fp16 store).
// 64 rows/block; wave w owns rows w*16..w*16+15; 4 n-tiles of 16; K=128 in
// 4 steps of 32.  A-frag: lane holds A[m=lane&15][k=quad*8+j].  B-frag from
// W^T[n][k] identically.  C/D: col=lane&15, row=quad*4+reg.
// ---------------------------------------------------------------------------
__global__ __launch_bounds__(256) void gemm_mfma(const float* __restrict__ x,
                                                 const float* __restrict__ w,
                                                 _Float16* __restrict__ support) {
    __shared__ _Float16 xb[GROUP_ROWS * LDK];   // 17.4 KB
    __shared__ _Float16 wt[OUT_DIM * LDK];      // 17.4 KB, wt[n][k]
    const int tid = threadIdx.x;

    // stage W^T as fp16 (8192 elements, coalesced global reads)
    for (int i = tid; i < IN_DIM * OUT_DIM; i += 256) {
        int k = i >> 6, n = i & 63;
        wt[n * LDK + k] = (_Float16)w[i];
    }
    // stage 64 rows of x as fp16 (float4 loads, h4 LDS stores)
    const int rowbase = blockIdx.x * GROUP_ROWS;
    for (int i = tid; i < GROUP_ROWS * (IN_DIM / 4); i += 256) {
        int r  = i >> 5;
        int kq = i & 31;
        int row = rowbase + r;
        float4 v = (row < N_NODES) ? *(const float4*)&x[(size_t)row * IN_DIM + kq * 4]
                                   : make_float4(0.f, 0.f, 0.f, 0.f);
        h4 hv = { (_Float16)v.x, (_Float16)v.y, (_Float16)v.z, (_Float16)v.w };
        *(h4*)&xb[r * LDK + kq * 4] = hv;
    }
    __syncthreads();

    const int wave = tid >> 6;
    const int lane = tid & 63;
    const int mrow = lane & 15;
    const int quad = lane >> 4;
    const int m0   = wave * 16;

    f4 acc[4];
    #pragma unroll
    for (int t = 0; t < 4; ++t) acc[t] = (f4){0.f, 0.f, 0.f, 0.f};

    #pragma unroll
    for (int ks = 0; ks < 4; ++ks) {
        int kof = ks * 32 + quad * 8;
        h8 a = *(h8*)&xb[(m0 + mrow) * LDK + kof];
        #pragma unroll
        for (int t = 0; t < 4; ++t) {
            h8 b = *(h8*)&wt[(t * 16 + mrow) * LDK + kof];
            acc[t] = __builtin_amdgcn_mfma_f32_16x16x32_f16(a, b, acc[t], 0, 0, 0);
        }
    }

    #pragma unroll
    for (int t = 0; t < 4; ++t) {
        #pragma unroll
        for (int r = 0; r < 4; ++r) {
            int row = rowbase + m0 + quad * 4 + r;
            if (row < N_NODES)
                support[(size_t)row * OUT_DIM + t * 16 + mrow] = (_Float16)acc[t][r];
        }
    }
}

// ---------------------------------------------------------------------------
// Phase 2a: slab fill (no pre-histogram / no scan).  Per block: LDS count,
// one global reservation per touched bin, place entries at
// bucket[g*SLAB + base + p].  Entry: x = (row&63)<<16 | col, y = val bits.
// ---------------------------------------------------------------------------
__global__ __launch_bounds__(256) void fill3_kernel(const int* __restrict__ erow,
                                                    const int* __restrict__ ecol,
                                                    const float* __restrict__ eval,
                                                    int* __restrict__ gcursor,
                                                    int2* __restrict__ bucket) {
    __shared__ int lcnt[N_GROUPS];
    __shared__ int lbase[N_GROUPS];
    for (int i = threadIdx.x; i < N_GROUPS; i += 256) lcnt[i] = 0;
    __syncthreads();
    const int base = blockIdx.x * CHUNK2;
    #pragma unroll 4
    for (int i = 0; i < CHUNK2 / 256; ++i) {
        int e = base + threadIdx.x + i * 256;
        if (e < N_EDGES) atomicAdd(&lcnt[erow[e] >> GROUP_SHIFT], 1);
    }
    __syncthreads();
    for (int i = threadIdx.x; i < N_GROUPS; i += 256) {
        int c = lcnt[i];
        lbase[i] = c ? atomicAdd(&gcursor[i], c) : 0;
        lcnt[i]  = 0;
    }
    __syncthreads();
    #pragma unroll 4
    for (int i = 0; i < CHUNK2 / 256; ++i) {
        int e = base + threadIdx.x + i * 256;
        if (e < N_EDGES) {
            int r = erow[e];
            int g = r >> GROUP_SHIFT;
            int p = atomicAdd(&lcnt[g], 1);
            bucket[(size_t)g * SLAB + lbase[g] + p] =
                make_int2(((r & (GROUP_ROWS - 1)) << 16) | ecol[e],
                          __float_as_int(eval[e]));
        }
    }
}

// ---------------------------------------------------------------------------
// Phase 2b: in-place per-group counting sort.  Stage slab to LDS, histogram
// the 64 local rows, wave-scan, write back row-sorted; emit (start,count).
// ---------------------------------------------------------------------------
__global__ __launch_bounds__(256) void sort3_kernel(const int* __restrict__ gcursor,
                                                    int2* __restrict__ bucket,
                                                    int2* __restrict__ offs_cnt) {
    __shared__ int2 ebuf[SLAB];            // 9.5 KB
    __shared__ int  rcnt[GROUP_ROWS];
    __shared__ int  rbase_s[GROUP_ROWS];
    const int grp   = blockIdx.x;
    const int cnt   = gcursor[grp];
    const long long start = (long long)grp * SLAB;
    const int tid   = threadIdx.x;

    if (tid < GROUP_ROWS) rcnt[tid] = 0;
    __syncthreads();
    for (int j = tid; j < cnt; j += 256) {
        int2 cv = bucket[start + j];
        ebuf[j] = cv;
        atomicAdd(&rcnt[cv.x >> 16], 1);
    }
    __syncthreads();
    if (tid < GROUP_ROWS) {
        int v = rcnt[tid];
        int s = v;
        #pragma unroll
        for (int off = 1; off < 64; off <<= 1) {
            int t = __shfl_up(s, off, 64);
            if (tid >= off) s += t;
        }
        int excl = s - v;
        rbase_s[tid] = excl;
        int row = grp * GROUP_ROWS + tid;
        if (row < N_NODES) offs_cnt[row] = make_int2((int)start + excl, v);
        rcnt[tid] = 0;   // reuse as cursor
    }
    __syncthreads();
    for (int j = tid; j < cnt; j += 256) {
        int2 cv = ebuf[j];
        int rl = cv.x >> 16;
        int p  = atomicAdd(&rcnt[rl], 1);
        bucket[start + rbase_s[rl] + p] = cv;
    }
}

// ---------------------------------------------------------------------------
// Phase 3: per-row gather-reduce + fused ReLU (register accumulation).
// ---------------------------------------------------------------------------
__global__ __launch_bounds__(256) void reduce_kernel(const int2* __restrict__ offs_cnt,
                                                     const int2* __restrict__ bucket,
                                                     const _Float16* __restrict__ support,
                                                     float* __restrict__ out) {
    const int g     = threadIdx.x & 15;
    const int local = threadIdx.x >> 4;
    const int row   = blockIdx.x * 16 + local;
    if (row >= N_NODES) return;
    const int2 oc   = offs_cnt[row];
    const int start = oc.x;
    const int end   = oc.x + oc.y;
    float4 acc = make_float4(0.f, 0.f, 0.f, 0.f);
    for (int j = start; j < end; ++j) {
        int2 cv = bucket[j];
        int col = cv.x & 0xFFFF;
        float v = __int_as_float(cv.y);
        h4 sr = *(const h4*)&support[(size_t)col * OUT_DIM + g * 4];
        acc.x += v * (float)sr[0];
        acc.y += v * (float)sr[1];
        acc.z += v * (float)sr[2];
        acc.w += v * (float)sr[3];
    }
    acc.x = fmaxf(acc.x, 0.f);
    acc.y = fmaxf(acc.y, 0.f);
    acc.z = fmaxf(acc.z, 0.f);
    acc.w = fmaxf(acc.w, 0.f);
    *(float4*)&out[(size_t)row * OUT_DIM + g * 4] = acc;
}

extern "C" void kernel_launch(void* const* d_in, const int* in_sizes, int n_in,
                              void* d_out, int out_size, void* d_ws, size_t ws_size,
                              hipStream_t stream) {
    const float* x    = (const float*)d_in[0];
    const int*   erow = (const int*)  d_in[1];
    const int*   ecol = (const int*)  d_in[2];
    const float* ev   = (const float*)d_in[3];
    const float* w    = (const float*)d_in[4];
    float* out = (float*)d_out;

    // workspace layout (16B-aligned), total ~14.4 MB
    char* ws = (char*)d_ws;
    _Float16* support = (_Float16*)ws;               //  6,400,000 B
    int*  gcursor  = (int*)(ws + 6400000);           //      3,128 B
    int2* offs_cnt = (int2*)(ws + 6403200);          //    400,000 B
    int2* bucket   = (int2*)(ws + 6803200);          //  7,607,296 B

    hipMemsetAsync(gcursor, 0, sizeof(int) * N_GROUPS, stream);

    gemm_mfma<<<N_GROUPS, 256, 0, stream>>>(x, w, support);
    fill3_kernel<<<FILL3_BLOCKS, 256, 0, stream>>>(erow, ecol, ev, gcursor, bucket);
    sort3_kernel<<<N_GROUPS, 256, 0, stream>>>(gcursor, bucket, offs_cnt);
    reduce_kernel<<<(N_NODES + 15) / 16, 256, 0, stream>>>(offs_cnt, bucket, support, out);
}

// Round 7
// 146.064 us; speedup vs baseline: 3.3590x; 1.0292x over previous
//
#include <hip/hip_runtime.h>

#define N_NODES 50000
#define N_EDGES 800000
#define IN_DIM 128
#define OUT_DIM 64

#define GROUP_SHIFT 6                 // 64 rows per group
#define GROUP_ROWS 64
#define N_GROUPS 782                  // ceil(50000/64)
#define SLAB 1216                     // slab capacity per group (mean 1024, +6 sigma)
#define CHUNK2 2048                   // edges per fill block
#define FILL3_BLOCKS 391              // 391*2048 >= 800000

typedef _Float16 h4 __attribute__((ext_vector_type(4)));
typedef _Float16 h8 __attribute__((ext_vector_type(8)));
typedef float    f4 __attribute__((ext_vector_type(4)));

#define LDK 136    // padded fp16 K-stride: 2-way bank alias only (free per m136)

// ---------------------------------------------------------------------------
// Phase 1: support = x @ weight via MFMA fp16 (fp32 accumulate, fp16 store).
// Also zeroes gcursor[blockIdx.x] (782 blocks == N_GROUPS bins), replacing
// the separate memset dispatch.
// ---------------------------------------------------------------------------
__global__ __launch_bounds__(256) void gemm_mfma(const float* __restrict__ x,
                                                 const float* __restrict__ w,
                                                 _Float16* __restrict__ support,
                                                 int* __restrict__ gcursor) {
    __shared__ _Float16 xb[GROUP_ROWS * LDK];
    __shared__ _Float16 wt[OUT_DIM * LDK];      // wt[n][k]
    const int tid = threadIdx.x;

    if (tid == 0) gcursor[blockIdx.x] = 0;      // fill3 runs strictly after

    for (int i = tid; i < IN_DIM * OUT_DIM; i += 256) {
        int k = i >> 6, n = i & 63;
        wt[n * LDK + k] = (_Float16)w[i];
    }
    const int rowbase = blockIdx.x * GROUP_ROWS;
    for (int i = tid; i < GROUP_ROWS * (IN_DIM / 4); i += 256) {
        int r  = i >> 5;
        int kq = i & 31;
        int row = rowbase + r;
        float4 v = (row < N_NODES) ? *(const float4*)&x[(size_t)row * IN_DIM + kq * 4]
                                   : make_float4(0.f, 0.f, 0.f, 0.f);
        h4 hv = { (_Float16)v.x, (_Float16)v.y, (_Float16)v.z, (_Float16)v.w };
        *(h4*)&xb[r * LDK + kq * 4] = hv;
    }
    __syncthreads();

    const int wave = tid >> 6;
    const int lane = tid & 63;
    const int mrow = lane & 15;
    const int quad = lane >> 4;
    const int m0   = wave * 16;

    f4 acc[4];
    #pragma unroll
    for (int t = 0; t < 4; ++t) acc[t] = (f4){0.f, 0.f, 0.f, 0.f};

    #pragma unroll
    for (int ks = 0; ks < 4; ++ks) {
        int kof = ks * 32 + quad * 8;
        h8 a = *(h8*)&xb[(m0 + mrow) * LDK + kof];
        #pragma unroll
        for (int t = 0; t < 4; ++t) {
            h8 b = *(h8*)&wt[(t * 16 + mrow) * LDK + kof];
            acc[t] = __builtin_amdgcn_mfma_f32_16x16x32_f16(a, b, acc[t], 0, 0, 0);
        }
    }

    #pragma unroll
    for (int t = 0; t < 4; ++t) {
        #pragma unroll
        for (int r = 0; r < 4; ++r) {
            int row = rowbase + m0 + quad * 4 + r;
            if (row < N_NODES)
                support[(size_t)row * OUT_DIM + t * 16 + mrow] = (_Float16)acc[t][r];
        }
    }
}

// ---------------------------------------------------------------------------
// Phase 2: slab fill.  Per block: LDS count, one global reservation per
// touched bin, place entries at bucket[g*SLAB + base + p].
// Entry: x = (row&63)<<16 | col, y = val bits.
// ---------------------------------------------------------------------------
__global__ __launch_bounds__(256) void fill3_kernel(const int* __restrict__ erow,
                                                    const int* __restrict__ ecol,
                                                    const float* __restrict__ eval,
                                                    int* __restrict__ gcursor,
                                                    int2* __restrict__ bucket) {
    __shared__ int lcnt[N_GROUPS];
    __shared__ int lbase[N_GROUPS];
    for (int i = threadIdx.x; i < N_GROUPS; i += 256) lcnt[i] = 0;
    __syncthreads();
    const int base = blockIdx.x * CHUNK2;
    #pragma unroll 4
    for (int i = 0; i < CHUNK2 / 256; ++i) {
        int e = base + threadIdx.x + i * 256;
        if (e < N_EDGES) atomicAdd(&lcnt[erow[e] >> GROUP_SHIFT], 1);
    }
    __syncthreads();
    for (int i = threadIdx.x; i < N_GROUPS; i += 256) {
        int c = lcnt[i];
        lbase[i] = c ? atomicAdd(&gcursor[i], c) : 0;
        lcnt[i]  = 0;
    }
    __syncthreads();
    #pragma unroll 4
    for (int i = 0; i < CHUNK2 / 256; ++i) {
        int e = base + threadIdx.x + i * 256;
        if (e < N_EDGES) {
            int r = erow[e];
            int g = r >> GROUP_SHIFT;
            int p = atomicAdd(&lcnt[g], 1);
            bucket[(size_t)g * SLAB + lbase[g] + p] =
                make_int2(((r & (GROUP_ROWS - 1)) << 16) | ecol[e],
                          __float_as_int(eval[e]));
        }
    }
}

// ---------------------------------------------------------------------------
// Phase 3 (fused sort+reduce): one block per 64-row group.
//  a) stage slab -> LDS ebuf, histogram 64 local rows
//  b) wave-0 scan -> rstart[65], cursors
//  c) row-sorted copy into LDS ebuf2 (never touches global)
//  d) register-accumulating per-row reduce: 16 col-lanes x 4 rows/thread,
//     h4 support gathers, fused ReLU, single coalesced writeout.
// ---------------------------------------------------------------------------
__global__ __launch_bounds__(256) void group_reduce(const int* __restrict__ gcursor,
                                                    const int2* __restrict__ bucket,
                                                    const _Float16* __restrict__ support,
                                                    float* __restrict__ out) {
    __shared__ int2 ebuf[SLAB];          // 9.5 KB
    __shared__ int2 ebuf2[SLAB];         // 9.5 KB (row-sorted)
    __shared__ int  rcnt[GROUP_ROWS];
    __shared__ int  rstart[GROUP_ROWS + 1];
    __shared__ int  rcur[GROUP_ROWS];
    const int grp = blockIdx.x;
    const int cnt = gcursor[grp];
    const long long start = (long long)grp * SLAB;
    const int tid = threadIdx.x;

    if (tid < GROUP_ROWS) rcnt[tid] = 0;
    __syncthreads();
    for (int j = tid; j < cnt; j += 256) {
        int2 cv = bucket[start + j];
        ebuf[j] = cv;
        atomicAdd(&rcnt[cv.x >> 16], 1);
    }
    __syncthreads();
    if (tid < GROUP_ROWS) {
        int v = rcnt[tid];
        int s = v;
        #pragma unroll
        for (int off = 1; off < 64; off <<= 1) {
            int t = __shfl_up(s, off, 64);
            if (tid >= off) s += t;
        }
        int excl = s - v;
        rstart[tid] = excl;
        rcur[tid]   = excl;
        if (tid == 63) rstart[64] = s;
    }
    __syncthreads();
    for (int j = tid; j < cnt; j += 256) {
        int2 cv = ebuf[j];
        int rl = cv.x >> 16;
        int p  = atomicAdd(&rcur[rl], 1);
        ebuf2[p] = cv;
    }
    __syncthreads();

    const int g     = tid & 15;       // colgroup: cols 4g..4g+3
    const int local = tid >> 4;       // 0..15
    const int rowbase = grp * GROUP_ROWS;
    #pragma unroll
    for (int rr = 0; rr < 4; ++rr) {
        const int rl  = local + rr * 16;
        const int row = rowbase + rl;
        const int jb  = rstart[rl];
        const int je  = rstart[rl + 1];
        float4 acc = make_float4(0.f, 0.f, 0.f, 0.f);
        for (int j = jb; j < je; ++j) {
            int2 cv = ebuf2[j];                       // broadcast across 16 lanes
            int col = cv.x & 0xFFFF;
            float v = __int_as_float(cv.y);
            h4 sr = *(const h4*)&support[(size_t)col * OUT_DIM + g * 4];
            acc.x += v * (float)sr[0];
            acc.y += v * (float)sr[1];
            acc.z += v * (float)sr[2];
            acc.w += v * (float)sr[3];
        }
        if (row < N_NODES) {
            acc.x = fmaxf(acc.x, 0.f);
            acc.y = fmaxf(acc.y, 0.f);
            acc.z = fmaxf(acc.z, 0.f);
            acc.w = fmaxf(acc.w, 0.f);
            *(float4*)&out[(size_t)row * OUT_DIM + g * 4] = acc;
        }
    }
}

extern "C" void kernel_launch(void* const* d_in, const int* in_sizes, int n_in,
                              void* d_out, int out_size, void* d_ws, size_t ws_size,
                              hipStream_t stream) {
    const float* x    = (const float*)d_in[0];
    const int*   erow = (const int*)  d_in[1];
    const int*   ecol = (const int*)  d_in[2];
    const float* ev   = (const float*)d_in[3];
    const float* w    = (const float*)d_in[4];
    float* out = (float*)d_out;

    // workspace layout (16B-aligned), total ~14.0 MB
    char* ws = (char*)d_ws;
    _Float16* support = (_Float16*)ws;               //  6,400,000 B
    int*  gcursor = (int*)(ws + 6400000);            //      3,128 B
    int2* bucket  = (int2*)(ws + 6403200);           //  7,607,296 B

    gemm_mfma<<<N_GROUPS, 256, 0, stream>>>(x, w, support, gcursor);
    fill3_kernel<<<FILL3_BLOCKS, 256, 0, stream>>>(erow, ecol, ev, gcursor, bucket);
    group_reduce<<<N_GROUPS, 256, 0, stream>>>(gcursor, bucket, support, out);
}

// Round 8
// 131.940 us; speedup vs baseline: 3.7186x; 1.1071x over previous
//
#include <hip/hip_runtime.h>

#define N_NODES 50000
#define N_EDGES 800000
#define IN_DIM 128
#define OUT_DIM 64

#define GROUP_SHIFT 6                 // 64 rows per group
#define GROUP_ROWS 64
#define N_GROUPS 782                  // ceil(50000/64)
#define SLAB 1216                     // slab capacity per group (mean 1024, +6 sigma)
#define CHUNK2 2048                   // edges per fill block
#define FILL_BLOCKS 391               // 391*2048 >= 800000

#define RPB 16                        // rows per reduce block
#define EB_CAP 448                    // per-16-row edge capacity (mean 256, +12 sigma)

typedef _Float16 h4 __attribute__((ext_vector_type(4)));
typedef _Float16 h8 __attribute__((ext_vector_type(8)));
typedef float    f4 __attribute__((ext_vector_type(4)));

#define LDK 136    // padded fp16 K-stride: 2-way bank alias only (free per m136)

// ---------------------------------------------------------------------------
// D1 (fused): blocks [0,782) do the MFMA fp16 GEMM for one 64-row group;
// blocks [782,1173) bin one 2048-edge chunk into the group slabs.
// The two roles are data-independent; fusing fills the machine (4.6 blk/CU)
// and hides the fill's atomic/memory latency under the GEMM.
// LDS is a 34816 B overlay: gemm = xb(17408)+wt(17408); fill = lcnt+lbase.
// ---------------------------------------------------------------------------
__global__ __launch_bounds__(256) void fused_gemm_fill(const float* __restrict__ x,
                                                       const float* __restrict__ w,
                                                       const int* __restrict__ erow,
                                                       const int* __restrict__ ecol,
                                                       const float* __restrict__ eval,
                                                       _Float16* __restrict__ support,
                                                       int* __restrict__ gcursor,
                                                       int2* __restrict__ bucket) {
    __shared__ char smem[GROUP_ROWS * LDK * 2 + OUT_DIM * LDK * 2];  // 34816 B
    const int tid = threadIdx.x;

    if (blockIdx.x < N_GROUPS) {
        // ---- GEMM role ----
        _Float16* xb = (_Float16*)smem;                       // [64][LDK]
        _Float16* wt = (_Float16*)(smem + GROUP_ROWS * LDK * 2); // [64][LDK], wt[n][k]

        for (int i = tid; i < IN_DIM * OUT_DIM; i += 256) {
            int k = i >> 6, n = i & 63;
            wt[n * LDK + k] = (_Float16)w[i];
        }
        const int rowbase = blockIdx.x * GROUP_ROWS;
        for (int i = tid; i < GROUP_ROWS * (IN_DIM / 4); i += 256) {
            int r  = i >> 5;
            int kq = i & 31;
            int row = rowbase + r;
            float4 v = (row < N_NODES)
                           ? *(const float4*)&x[(size_t)row * IN_DIM + kq * 4]
                           : make_float4(0.f, 0.f, 0.f, 0.f);
            h4 hv = { (_Float16)v.x, (_Float16)v.y, (_Float16)v.z, (_Float16)v.w };
            *(h4*)&xb[r * LDK + kq * 4] = hv;
        }
        __syncthreads();

        const int wave = tid >> 6;
        const int lane = tid & 63;
        const int mrow = lane & 15;
        const int quad = lane >> 4;
        const int m0   = wave * 16;

        f4 acc[4];
        #pragma unroll
        for (int t = 0; t < 4; ++t) acc[t] = (f4){0.f, 0.f, 0.f, 0.f};

        #pragma unroll
        for (int ks = 0; ks < 4; ++ks) {
            int kof = ks * 32 + quad * 8;
            h8 a = *(h8*)&xb[(m0 + mrow) * LDK + kof];
            #pragma unroll
            for (int t = 0; t < 4; ++t) {
                h8 b = *(h8*)&wt[(t * 16 + mrow) * LDK + kof];
                acc[t] = __builtin_amdgcn_mfma_f32_16x16x32_f16(a, b, acc[t], 0, 0, 0);
            }
        }

        #pragma unroll
        for (int t = 0; t < 4; ++t) {
            #pragma unroll
            for (int r = 0; r < 4; ++r) {
                int row = rowbase + m0 + quad * 4 + r;
                if (row < N_NODES)
                    support[(size_t)row * OUT_DIM + t * 16 + mrow] = (_Float16)acc[t][r];
            }
        }
    } else {
        // ---- fill role ----
        int* lcnt  = (int*)smem;          // [N_GROUPS]
        int* lbase = lcnt + N_GROUPS;     // [N_GROUPS]
        for (int i = tid; i < N_GROUPS; i += 256) lcnt[i] = 0;
        __syncthreads();
        const int base = (blockIdx.x - N_GROUPS) * CHUNK2;
        #pragma unroll 4
        for (int i = 0; i < CHUNK2 / 256; ++i) {
            int e = base + tid + i * 256;
            if (e < N_EDGES) atomicAdd(&lcnt[erow[e] >> GROUP_SHIFT], 1);
        }
        __syncthreads();
        for (int i = tid; i < N_GROUPS; i += 256) {
            int c = lcnt[i];
            lbase[i] = c ? atomicAdd(&gcursor[i], c) : 0;
            lcnt[i]  = 0;
        }
        __syncthreads();
        #pragma unroll 4
        for (int i = 0; i < CHUNK2 / 256; ++i) {
            int e = base + tid + i * 256;
            if (e < N_EDGES) {
                int r = erow[e];
                int g = r >> GROUP_SHIFT;
                int p = atomicAdd(&lcnt[g], 1);
                bucket[(size_t)g * SLAB + lbase[g] + p] =
                    make_int2(((r & (GROUP_ROWS - 1)) << 16) | ecol[e],
                              __float_as_int(eval[e]));
            }
        }
    }
}

// ---------------------------------------------------------------------------
// D2: reduce, 16 rows per block (4 sub-blocks per group, 3128 blocks ~ 12/CU).
// Each block scans its group's slab from global (L2-hot, written by D1),
// filters its 16 rows, sorts them into a 3.5 KB LDS buffer, then reduces
// with exactly ONE row per thread (16 rows x 16 col-lanes), fused ReLU.
// ---------------------------------------------------------------------------
__global__ __launch_bounds__(256) void reduce16(const int* __restrict__ gcursor,
                                                const int2* __restrict__ bucket,
                                                const _Float16* __restrict__ support,
                                                float* __restrict__ out) {
    __shared__ int2 ebuf[EB_CAP];
    __shared__ int  rcnt[RPB];
    __shared__ int  rstart[RPB + 1];
    __shared__ int  rcur[RPB];
    const int grp = blockIdx.x >> 2;
    const int sub = blockIdx.x & 3;
    const int cnt = min(gcursor[grp], SLAB);
    const size_t sb = (size_t)grp * SLAB;
    const int tid = threadIdx.x;

    if (tid < RPB) rcnt[tid] = 0;
    __syncthreads();
    // pass 1: count this sub-block's rows
    for (int j = tid; j < cnt; j += 256) {
        int rl = bucket[sb + j].x >> 16;
        if ((rl >> 4) == sub) atomicAdd(&rcnt[rl & 15], 1);
    }
    __syncthreads();
    // tiny scan of 16 counts (lanes 0..15 of wave 0)
    if (tid < RPB) {
        int v = rcnt[tid];
        int s = v;
        #pragma unroll
        for (int off = 1; off < RPB; off <<= 1) {
            int t = __shfl_up(s, off, 64);
            if (tid >= off) s += t;
        }
        rstart[tid] = s - v;
        rcur[tid]   = s - v;
        if (tid == RPB - 1) rstart[RPB] = s;
    }
    __syncthreads();
    // pass 2: re-read slab (L2-hot) and place row-sorted into LDS
    for (int j = tid; j < cnt; j += 256) {
        int2 cv = bucket[sb + j];
        int rl = cv.x >> 16;
        if ((rl >> 4) == sub) {
            int p = atomicAdd(&rcur[rl & 15], 1);
            if (p < EB_CAP) ebuf[p] = cv;
        }
    }
    __syncthreads();

    // reduce: one row per thread
    const int g  = tid & 15;          // col group: cols 4g..4g+3
    const int lr = tid >> 4;          // 0..15 local row
    const int row = grp * GROUP_ROWS + sub * RPB + lr;
    const int jb = rstart[lr];
    const int je = min(rstart[lr + 1], EB_CAP);
    float4 acc = make_float4(0.f, 0.f, 0.f, 0.f);
    for (int j = jb; j < je; ++j) {
        int2 cv = ebuf[j];                            // broadcast across 16 lanes
        int col = cv.x & 0xFFFF;
        float v = __int_as_float(cv.y);
        h4 sr = *(const h4*)&support[(size_t)col * OUT_DIM + g * 4];
        acc.x += v * (float)sr[0];
        acc.y += v * (float)sr[1];
        acc.z += v * (float)sr[2];
        acc.w += v * (float)sr[3];
    }
    if (row < N_NODES) {
        acc.x = fmaxf(acc.x, 0.f);
        acc.y = fmaxf(acc.y, 0.f);
        acc.z = fmaxf(acc.z, 0.f);
        acc.w = fmaxf(acc.w, 0.f);
        *(float4*)&out[(size_t)row * OUT_DIM + g * 4] = acc;
    }
}

extern "C" void kernel_launch(void* const* d_in, const int* in_sizes, int n_in,
                              void* d_out, int out_size, void* d_ws, size_t ws_size,
                              hipStream_t stream) {
    const float* x    = (const float*)d_in[0];
    const int*   erow = (const int*)  d_in[1];
    const int*   ecol = (const int*)  d_in[2];
    const float* ev   = (const float*)d_in[3];
    const float* w    = (const float*)d_in[4];
    float* out = (float*)d_out;

    // workspace layout (16B-aligned), total ~14.0 MB
    char* ws = (char*)d_ws;
    _Float16* support = (_Float16*)ws;               //  6,400,000 B
    int*  gcursor = (int*)(ws + 6400000);            //      3,128 B
    int2* bucket  = (int2*)(ws + 6403200);           //  7,607,296 B

    hipMemsetAsync(gcursor, 0, sizeof(int) * N_GROUPS, stream);

    fused_gemm_fill<<<N_GROUPS + FILL_BLOCKS, 256, 0, stream>>>(
        x, w, erow, ecol, ev, support, gcursor, bucket);

    reduce16<<<N_GROUPS * 4, 256, 0, stream>>>(gcursor, bucket, support, out);
}

// Round 9
// 130.436 us; speedup vs baseline: 3.7615x; 1.0115x over previous
//
#include <hip/hip_runtime.h>

#define N_NODES 50000
#define N_EDGES 800000
#define IN_DIM 128
#define OUT_DIM 64

#define GROUP_SHIFT 6                 // 64 rows per group
#define GROUP_ROWS 64
#define N_GROUPS 782                  // ceil(50000/64)
#define SLAB 1216                     // slab capacity per group (mean 1024, +6 sigma)
#define CHUNK2 2048                   // edges per fill block
#define FILL_BLOCKS 391               // 391*2048 >= 800000

typedef _Float16 h4 __attribute__((ext_vector_type(4)));
typedef _Float16 h8 __attribute__((ext_vector_type(8)));
typedef float    f4 __attribute__((ext_vector_type(4)));

#define LDK 136    // padded fp16 K-stride: 2-way bank alias only (free per m136)

// ---------------------------------------------------------------------------
// D1 (fused): blocks [0,782) = MFMA fp16 GEMM for one 64-row group;
// blocks [782,1173) = bin one 2048-edge chunk into the group slabs.
// Data-independent roles; fusing fills the machine (4.6 blk/CU) and hides
// fill's atomic/memory latency under the GEMM.
// ---------------------------------------------------------------------------
__global__ __launch_bounds__(256) void fused_gemm_fill(const float* __restrict__ x,
                                                       const float* __restrict__ w,
                                                       const int* __restrict__ erow,
                                                       const int* __restrict__ ecol,
                                                       const float* __restrict__ eval,
                                                       _Float16* __restrict__ support,
                                                       int* __restrict__ gcursor,
                                                       int2* __restrict__ bucket) {
    __shared__ char smem[GROUP_ROWS * LDK * 2 + OUT_DIM * LDK * 2];  // 34816 B
    const int tid = threadIdx.x;

    if (blockIdx.x < N_GROUPS) {
        // ---- GEMM role ----
        _Float16* xb = (_Float16*)smem;
        _Float16* wt = (_Float16*)(smem + GROUP_ROWS * LDK * 2);  // wt[n][k]

        for (int i = tid; i < IN_DIM * OUT_DIM; i += 256) {
            int k = i >> 6, n = i & 63;
            wt[n * LDK + k] = (_Float16)w[i];
        }
        const int rowbase = blockIdx.x * GROUP_ROWS;
        for (int i = tid; i < GROUP_ROWS * (IN_DIM / 4); i += 256) {
            int r  = i >> 5;
            int kq = i & 31;
            int row = rowbase + r;
            float4 v = (row < N_NODES)
                           ? *(const float4*)&x[(size_t)row * IN_DIM + kq * 4]
                           : make_float4(0.f, 0.f, 0.f, 0.f);
            h4 hv = { (_Float16)v.x, (_Float16)v.y, (_Float16)v.z, (_Float16)v.w };
            *(h4*)&xb[r * LDK + kq * 4] = hv;
        }
        __syncthreads();

        const int wave = tid >> 6;
        const int lane = tid & 63;
        const int mrow = lane & 15;
        const int quad = lane >> 4;
        const int m0   = wave * 16;

        f4 acc[4];
        #pragma unroll
        for (int t = 0; t < 4; ++t) acc[t] = (f4){0.f, 0.f, 0.f, 0.f};

        #pragma unroll
        for (int ks = 0; ks < 4; ++ks) {
            int kof = ks * 32 + quad * 8;
            h8 a = *(h8*)&xb[(m0 + mrow) * LDK + kof];
            #pragma unroll
            for (int t = 0; t < 4; ++t) {
                h8 b = *(h8*)&wt[(t * 16 + mrow) * LDK + kof];
                acc[t] = __builtin_amdgcn_mfma_f32_16x16x32_f16(a, b, acc[t], 0, 0, 0);
            }
        }

        #pragma unroll
        for (int t = 0; t < 4; ++t) {
            #pragma unroll
            for (int r = 0; r < 4; ++r) {
                int row = rowbase + m0 + quad * 4 + r;
                if (row < N_NODES)
                    support[(size_t)row * OUT_DIM + t * 16 + mrow] = (_Float16)acc[t][r];
            }
        }
    } else {
        // ---- fill role ----
        int* lcnt  = (int*)smem;
        int* lbase = lcnt + N_GROUPS;
        for (int i = tid; i < N_GROUPS; i += 256) lcnt[i] = 0;
        __syncthreads();
        const int base = (blockIdx.x - N_GROUPS) * CHUNK2;
        #pragma unroll 4
        for (int i = 0; i < CHUNK2 / 256; ++i) {
            int e = base + tid + i * 256;
            if (e < N_EDGES) atomicAdd(&lcnt[erow[e] >> GROUP_SHIFT], 1);
        }
        __syncthreads();
        for (int i = tid; i < N_GROUPS; i += 256) {
            int c = lcnt[i];
            lbase[i] = c ? atomicAdd(&gcursor[i], c) : 0;
            lcnt[i]  = 0;
        }
        __syncthreads();
        #pragma unroll 4
        for (int i = 0; i < CHUNK2 / 256; ++i) {
            int e = base + tid + i * 256;
            if (e < N_EDGES) {
                int r = erow[e];
                int g = r >> GROUP_SHIFT;
                int p = atomicAdd(&lcnt[g], 1);
                bucket[(size_t)g * SLAB + lbase[g] + p] =
                    make_int2(((r & (GROUP_ROWS - 1)) << 16) | ecol[e],
                              __float_as_int(eval[e]));
            }
        }
    }
}

// ---------------------------------------------------------------------------
// D2: one 1024-thread block per 64-row group (2 blocks/CU = 32 waves, full
// occupancy).  Slab staged to LDS ONCE; histogram + wave-0 scan + one in-LDS
// counting sort; then exactly one (row, colgroup) per thread: 64 rows x 16
// col-lanes = 1024.  Entry reads broadcast across a row's 16 lanes (free).
// ---------------------------------------------------------------------------
__global__ __launch_bounds__(1024) void reduce_group(const int* __restrict__ gcursor,
                                                     const int2* __restrict__ bucket,
                                                     const _Float16* __restrict__ support,
                                                     float* __restrict__ out) {
    __shared__ int2 ebuf[SLAB];            // 9.7 KB staged slab
    __shared__ int2 ebuf2[SLAB];           // 9.7 KB row-sorted
    __shared__ int  rcnt[GROUP_ROWS];
    __shared__ int  rstart[GROUP_ROWS + 1];
    __shared__ int  rcur[GROUP_ROWS];
    const int grp = blockIdx.x;
    const int cnt = min(gcursor[grp], SLAB);
    const size_t sb = (size_t)grp * SLAB;
    const int tid = threadIdx.x;

    if (tid < GROUP_ROWS) rcnt[tid] = 0;
    __syncthreads();
    for (int j = tid; j < cnt; j += 1024) {
        int2 cv = bucket[sb + j];
        ebuf[j] = cv;
        atomicAdd(&rcnt[cv.x >> 16], 1);
    }
    __syncthreads();
    if (tid < GROUP_ROWS) {              // wave 0 scans the 64 row counts
        int v = rcnt[tid];
        int s = v;
        #pragma unroll
        for (int off = 1; off < 64; off <<= 1) {
            int t = __shfl_up(s, off, 64);
            if (tid >= off) s += t;
        }
        rstart[tid] = s - v;
        rcur[tid]   = s - v;
        if (tid == 63) rstart[64] = s;
    }
    __syncthreads();
    for (int j = tid; j < cnt; j += 1024) {
        int2 cv = ebuf[j];
        int rl = cv.x >> 16;
        int p  = atomicAdd(&rcur[rl], 1);
        ebuf2[p] = cv;
    }
    __syncthreads();

    // reduce: one (row, colgroup) per thread
    const int g  = tid & 15;             // cols 4g..4g+3
    const int lr = tid >> 4;             // local row 0..63
    const int row = grp * GROUP_ROWS + lr;
    const int jb = rstart[lr];
    const int je = rstart[lr + 1];
    float4 acc = make_float4(0.f, 0.f, 0.f, 0.f);
    for (int j = jb; j < je; ++j) {
        int2 cv = ebuf2[j];              // same address for the row's 16 lanes
        int col = cv.x & 0xFFFF;
        float v = __int_as_float(cv.y);
        h4 sr = *(const h4*)&support[(size_t)col * OUT_DIM + g * 4];
        acc.x += v * (float)sr[0];
        acc.y += v * (float)sr[1];
        acc.z += v * (float)sr[2];
        acc.w += v * (float)sr[3];
    }
    if (row < N_NODES) {
        acc.x = fmaxf(acc.x, 0.f);
        acc.y = fmaxf(acc.y, 0.f);
        acc.z = fmaxf(acc.z, 0.f);
        acc.w = fmaxf(acc.w, 0.f);
        *(float4*)&out[(size_t)row * OUT_DIM + g * 4] = acc;
    }
}

extern "C" void kernel_launch(void* const* d_in, const int* in_sizes, int n_in,
                              void* d_out, int out_size, void* d_ws, size_t ws_size,
                              hipStream_t stream) {
    const float* x    = (const float*)d_in[0];
    const int*   erow = (const int*)  d_in[1];
    const int*   ecol = (const int*)  d_in[2];
    const float* ev   = (const float*)d_in[3];
    const float* w    = (const float*)d_in[4];
    float* out = (float*)d_out;

    // workspace layout (16B-aligned), total ~14.0 MB
    char* ws = (char*)d_ws;
    _Float16* support = (_Float16*)ws;               //  6,400,000 B
    int*  gcursor = (int*)(ws + 6400000);            //      3,128 B
    int2* bucket  = (int2*)(ws + 6403200);           //  7,607,296 B

    hipMemsetAsync(gcursor, 0, sizeof(int) * N_GROUPS, stream);

    fused_gemm_fill<<<N_GROUPS + FILL_BLOCKS, 256, 0, stream>>>(
        x, w, erow, ecol, ev, support, gcursor, bucket);

    reduce_group<<<N_GROUPS, 1024, 0, stream>>>(gcursor, bucket, support, out);
}